// Round 13
// baseline (305.166 us; speedup 1.0000x reference)
//
#include <hip/hip_runtime.h>
#include <math.h>

#define NEG_SLOPE 0.2f
#define SM_EPS 1e-16f

typedef short short8 __attribute__((ext_vector_type(8)));
typedef float floatx4 __attribute__((ext_vector_type(4)));

// ---------------- helpers ----------------

__device__ inline unsigned short f2bf(float x) {
    unsigned int u = __float_as_uint(x);
    unsigned int r = (u + 0x7FFFu + ((u >> 16) & 1u)) >> 16;
    return (unsigned short)r;
}

__device__ inline float bf2f(unsigned short h) {
    return __uint_as_float(((unsigned int)h) << 16);
}

__device__ inline float bflo(unsigned int u) { return __uint_as_float(u << 16); }
__device__ inline float bfhi(unsigned int u) { return __uint_as_float(u & 0xFFFF0000u); }

// async global->LDS 16B copy: LDS dst = wave-uniform base + lane*16
__device__ __forceinline__ void gl_lds16(const unsigned short* g, unsigned short* l) {
    __builtin_amdgcn_global_load_lds(
        (const __attribute__((address_space(1))) unsigned int*)(g),
        (__attribute__((address_space(3))) unsigned int*)(l), 16, 0, 0);
}

__device__ inline void get_edge(const int* __restrict__ srcA, const int* __restrict__ dstA,
                                int e, int E, int& s, int& d) {
    if (e < E) { s = srcA[e]; d = dstA[e]; }
    else { s = e - E; d = e - E; }   // self-loops appended after real edges
}

// ---------------- fused prep: deg histogram | x->bf16 | W1t | W2t ----------------

__global__ __launch_bounds__(256) void k_prep(const float* __restrict__ x,
                                              unsigned short* __restrict__ xb,
                                              const float* __restrict__ W1,
                                              unsigned short* __restrict__ w1t,
                                              const float* __restrict__ W2,
                                              unsigned short* __restrict__ w2bt,
                                              const int* __restrict__ dstA,
                                              int E, int Ep,
                                              int* __restrict__ deg,
                                              int nblk_deg, int nblk_x) {
    __shared__ float tile[32][33];
    int bx = blockIdx.x;
    int t = threadIdx.x;
    if (bx < nblk_deg) {
        int e = bx * 256 + t;
        if (e < Ep) {
            int d = (e < E) ? dstA[e] : (e - E);
            atomicAdd(&deg[d], 1);
        }
    } else if (bx < nblk_deg + nblk_x) {
        int i = ((bx - nblk_deg) * 256 + t) * 4;
        float4 v = *(const float4*)(x + i);
        ushort4 o;
        o.x = f2bf(v.x); o.y = f2bf(v.y); o.z = f2bf(v.z); o.w = f2bf(v.w);
        *(ushort4*)(xb + i) = o;
    } else if (bx < nblk_deg + nblk_x + 256) {
        int b = bx - nblk_deg - nblk_x;          // 0..255
        int kb = (b & 15) * 32;                  // k base
        int nb = (b >> 4) * 32;                  // n base
        int tx = t & 31, ty = t >> 5;            // 32x8
        #pragma unroll
        for (int i = 0; i < 32; i += 8)
            tile[ty + i][tx] = W1[(size_t)(kb + ty + i) * 512 + nb + tx];
        __syncthreads();
        #pragma unroll
        for (int i = 0; i < 32; i += 8)
            w1t[(size_t)(nb + ty + i) * 512 + kb + tx] = f2bf(tile[tx][ty + i]);
    } else {
        int i = (bx - nblk_deg - nblk_x - 256) * 256 + t;   // 0..16383
        int c = i >> 9, k = i & 511;
        w2bt[i] = f2bf(W2[k * 32 + c]);
    }
}

// ---------------- CSR build + degree-bin histogram ----------------

__global__ __launch_bounds__(256) void k_scan1(const int* __restrict__ deg, int* __restrict__ incl,
                                               int* __restrict__ part, int* __restrict__ bins, int N) {
    __shared__ int sm[256];
    __shared__ int hist[64];
    int t = threadIdx.x;
    if (t < 64) hist[t] = 0;
    int i = blockIdx.x * 256 + t;
    int v = (i < N) ? deg[i] : 0;
    sm[t] = v;
    __syncthreads();
    if (i < N) atomicAdd(&hist[v < 63 ? v : 63], 1);
    for (int o = 1; o < 256; o <<= 1) {
        int x = (t >= o) ? sm[t - o] : 0;
        __syncthreads();
        sm[t] += x;
        __syncthreads();
    }
    if (i < N) incl[i] = sm[t];
    if (t == 255) part[blockIdx.x] = sm[255];
    __syncthreads();
    if (t < 64 && hist[t]) atomicAdd(&bins[t], hist[t]);
}

// exclusive prefix over the 64 degree bins -> bin cursors
__global__ void k_binscan(const int* __restrict__ bins, int* __restrict__ bincur) {
    if (threadIdx.x == 0) {
        int run = 0;
        for (int i = 0; i < 64; ++i) { bincur[i] = run; run += bins[i]; }
    }
}

// scan3 with inlined partial-prefix
__global__ __launch_bounds__(256) void k_scan3(const int* __restrict__ incl, const int* __restrict__ part,
                                               const int* __restrict__ deg, int* __restrict__ off,
                                               int* __restrict__ cursor, int N) {
    __shared__ int sm[256];
    int bx = blockIdx.x, t = threadIdx.x;
    int partial = 0;
    for (int i = t; i < bx; i += 256) partial += part[i];
    sm[t] = partial; __syncthreads();
    for (int o = 128; o > 0; o >>= 1) {
        if (t < o) sm[t] += sm[t + o];
        __syncthreads();
    }
    int base = sm[0];
    int i = bx * 256 + t;
    if (i >= N) return;
    int v = incl[i] + base;   // inclusive scan value
    off[i + 1] = v;
    cursor[i] = v - deg[i];
    if (i == 0) off[0] = 0;
}

// edge scatter + (tail blocks) degree-binned node permutation
__global__ __launch_bounds__(256) void k_scatter(const int* __restrict__ srcA, const int* __restrict__ dstA,
                                                 int E, int Ep, int* __restrict__ cursor,
                                                 int* __restrict__ src_s,
                                                 const int* __restrict__ deg,
                                                 int* __restrict__ bincur, int* __restrict__ perm,
                                                 int nblk_e, int N) {
    int bx = blockIdx.x, t = threadIdx.x;
    if (bx < nblk_e) {
        int e = bx * 256 + t;
        if (e >= Ep) return;
        int s, d; get_edge(srcA, dstA, e, E, s, d);
        int p = atomicAdd(&cursor[d], 1);
        src_s[p] = s;
    } else {
        int i = (bx - nblk_e) * 256 + t;
        if (i >= N) return;
        int b = deg[i]; b = b < 63 ? b : 63;
        int pos = atomicAdd(&bincur[b], 1);
        perm[pos] = i;
    }
}

// ---------------- GEMM1 (bf16 MFMA, global_load_lds staging) + fused attn1 ----------------
// attn dots stored HEAD-MAJOR: a_sd[h*N + r], a_dd[h*N + r].

__global__ __launch_bounds__(256) void k_gemm1_mfma(const unsigned short* __restrict__ A,
                                                    const unsigned short* __restrict__ Bt,
                                                    const float* __restrict__ att_s,
                                                    const float* __restrict__ att_d,
                                                    unsigned short* __restrict__ C,
                                                    float* __restrict__ a_sd,
                                                    float* __restrict__ a_dd, int M) {
    const int K = 512;
    __shared__ unsigned short As[128 * 32];
    __shared__ unsigned short Bs[128 * 32];
    int t = threadIdx.x;
    int lane = t & 63;
    int w = t >> 6;
    int row0 = blockIdx.x * 128;
    int col0 = blockIdx.y * 128;
    int wm = (w >> 1) * 64, wn = (w & 1) * 64;
    int l15 = lane & 15, q = lane >> 4;

    int mrow = t >> 2;            // 0..63
    int kk = (t & 3) * 8;
    unsigned short* ldsA0 = &As[w * 512];
    unsigned short* ldsA1 = &As[2048 + w * 512];
    unsigned short* ldsB0 = &Bs[w * 512];
    unsigned short* ldsB1 = &Bs[2048 + w * 512];

    floatx4 acc[4][4] = {};

    for (int k0 = 0; k0 < K; k0 += 32) {
        gl_lds16(A  + (size_t)(row0 + mrow) * K + k0 + kk,      ldsA0);
        gl_lds16(A  + (size_t)(row0 + 64 + mrow) * K + k0 + kk, ldsA1);
        gl_lds16(Bt + (size_t)(col0 + mrow) * K + k0 + kk,      ldsB0);
        gl_lds16(Bt + (size_t)(col0 + 64 + mrow) * K + k0 + kk, ldsB1);
        __syncthreads();
        short8 af[4], bfr[4];
        #pragma unroll
        for (int i = 0; i < 4; ++i)
            af[i] = *(const short8*)(&As[(wm + i * 16 + l15) * 32 + q * 8]);
        #pragma unroll
        for (int j = 0; j < 4; ++j)
            bfr[j] = *(const short8*)(&Bs[(wn + j * 16 + l15) * 32 + q * 8]);
        #pragma unroll
        for (int i = 0; i < 4; ++i)
            #pragma unroll
            for (int j = 0; j < 4; ++j)
                acc[i][j] = __builtin_amdgcn_mfma_f32_16x16x32_bf16(af[i], bfr[j], acc[i][j], 0, 0, 0);
        __syncthreads();
    }

    #pragma unroll
    for (int i = 0; i < 4; ++i) {
        #pragma unroll
        for (int p = 0; p < 4; ++p) {
            int r = row0 + wm + i * 16 + q * 4 + p;
            if (r < M) {
                #pragma unroll
                for (int j = 0; j < 4; ++j) {
                    int c = col0 + wn + j * 16 + l15;
                    C[(size_t)r * 512 + c] = f2bf(acc[i][j][p]);
                }
            }
        }
    }

    int hh = blockIdx.y * 2 + (w & 1);
    float asr[4], adr[4];
    #pragma unroll
    for (int j = 0; j < 4; ++j) {
        asr[j] = att_s[hh * 64 + j * 16 + l15];
        adr[j] = att_d[hh * 64 + j * 16 + l15];
    }
    #pragma unroll
    for (int i = 0; i < 4; ++i) {
        #pragma unroll
        for (int p = 0; p < 4; ++p) {
            float ds = 0.f, dd = 0.f;
            #pragma unroll
            for (int j = 0; j < 4; ++j) {
                ds = fmaf(acc[i][j][p], asr[j], ds);
                dd = fmaf(acc[i][j][p], adr[j], dd);
            }
            #pragma unroll
            for (int mk = 1; mk <= 8; mk <<= 1) {
                ds += __shfl_xor(ds, mk);
                dd += __shfl_xor(dd, mk);
            }
            int r = row0 + wm + i * 16 + q * 4 + p;
            if (l15 == 0 && r < M) {
                a_sd[(size_t)hh * M + r] = ds;
                a_dd[(size_t)hh * M + r] = dd;
            }
        }
    }
}

// ---------------- layer-1: head-sliced, lane-private, degree-binned ----------------
// Wave = 8 nodes x 1 head via perm[] (degree-sorted -> near-equal degrees per wave).
// head = blockIdx.x & 7 -> XCD affinity. Zero cross-lane ops.

__global__ __launch_bounds__(256) void k_l1(const unsigned short* __restrict__ xw,
                                            const float* __restrict__ a_s,
                                            const float* __restrict__ a_d,
                                            const int* __restrict__ off,
                                            const int* __restrict__ src_s,
                                            const int* __restrict__ perm,
                                            const float* __restrict__ bias,
                                            unsigned short* __restrict__ hout, int N) {
    int wid = threadIdx.x >> 6, lane = threadIdx.x & 63;
    int h = blockIdx.x & 7;
    int slot = (blockIdx.x >> 3) * 32 + wid * 8 + (lane >> 3);
    int li = lane & 7;
    if (slot >= N) return;
    int n = perm[slot];
    int p0 = off[n], p1 = off[n + 1];
    const float* ash = a_s + (size_t)h * N;
    float adv = a_d[(size_t)h * N + n];
    const size_t cbase = (size_t)h * 64 + (size_t)li * 8;

    float acc[8] = {};
    float s = 0.f;
    int p = p0;
    for (; p + 2 <= p1; p += 2) {
        int s0 = src_s[p];
        int s1 = src_s[p + 1];
        const uint4 u0 = *(const uint4*)(xw + (size_t)s0 * 512 + cbase);
        const uint4 u1 = *(const uint4*)(xw + (size_t)s1 * 512 + cbase);
        float e0 = ash[s0] + adv; e0 = e0 > 0.f ? e0 : NEG_SLOPE * e0;
        float e1 = ash[s1] + adv; e1 = e1 > 0.f ? e1 : NEG_SLOPE * e1;
        float w0 = __expf(e0);
        float w1 = __expf(e1);
        s += w0 + w1;
        acc[0] = fmaf(w0, bflo(u0.x), acc[0]); acc[1] = fmaf(w0, bfhi(u0.x), acc[1]);
        acc[2] = fmaf(w0, bflo(u0.y), acc[2]); acc[3] = fmaf(w0, bfhi(u0.y), acc[3]);
        acc[4] = fmaf(w0, bflo(u0.z), acc[4]); acc[5] = fmaf(w0, bfhi(u0.z), acc[5]);
        acc[6] = fmaf(w0, bflo(u0.w), acc[6]); acc[7] = fmaf(w0, bfhi(u0.w), acc[7]);
        acc[0] = fmaf(w1, bflo(u1.x), acc[0]); acc[1] = fmaf(w1, bfhi(u1.x), acc[1]);
        acc[2] = fmaf(w1, bflo(u1.y), acc[2]); acc[3] = fmaf(w1, bfhi(u1.y), acc[3]);
        acc[4] = fmaf(w1, bflo(u1.z), acc[4]); acc[5] = fmaf(w1, bfhi(u1.z), acc[5]);
        acc[6] = fmaf(w1, bflo(u1.w), acc[6]); acc[7] = fmaf(w1, bfhi(u1.w), acc[7]);
    }
    if (p < p1) {
        int s0 = src_s[p];
        const uint4 u0 = *(const uint4*)(xw + (size_t)s0 * 512 + cbase);
        float e0 = ash[s0] + adv; e0 = e0 > 0.f ? e0 : NEG_SLOPE * e0;
        float w0 = __expf(e0);
        s += w0;
        acc[0] = fmaf(w0, bflo(u0.x), acc[0]); acc[1] = fmaf(w0, bfhi(u0.x), acc[1]);
        acc[2] = fmaf(w0, bflo(u0.y), acc[2]); acc[3] = fmaf(w0, bfhi(u0.y), acc[3]);
        acc[4] = fmaf(w0, bflo(u0.z), acc[4]); acc[5] = fmaf(w0, bfhi(u0.z), acc[5]);
        acc[6] = fmaf(w0, bflo(u0.w), acc[6]); acc[7] = fmaf(w0, bfhi(u0.w), acc[7]);
    }

    float inv = 1.f / (s + SM_EPS);
    unsigned int ov[4];
    #pragma unroll
    for (int j = 0; j < 4; ++j) {
        float v0 = acc[2 * j] * inv     + bias[cbase + 2 * j];
        float v1 = acc[2 * j + 1] * inv + bias[cbase + 2 * j + 1];
        v0 = v0 > 0.f ? v0 : __expf(v0) - 1.f;
        v1 = v1 > 0.f ? v1 : __expf(v1) - 1.f;
        ov[j] = (unsigned int)f2bf(v0) | ((unsigned int)f2bf(v1) << 16);
    }
    *(uint4*)(hout + (size_t)n * 512 + cbase) = make_uint4(ov[0], ov[1], ov[2], ov[3]);
}

// ---------------- GEMM2 (bf16 MFMA) + fused attn2; hw2 stored bf16 ----------------

__global__ __launch_bounds__(256) void k_gemm2_mfma(const unsigned short* __restrict__ A,
                                                    const unsigned short* __restrict__ Bt,
                                                    const float* __restrict__ att_s,
                                                    const float* __restrict__ att_d,
                                                    unsigned short* __restrict__ O,
                                                    float* __restrict__ a_s, float* __restrict__ a_d,
                                                    int M) {
    const int K = 512;
    __shared__ unsigned short As[64 * 40];
    __shared__ unsigned short Bs[32 * 40];
    int t = threadIdx.x;
    int lane = t & 63;
    int w = t >> 6;
    int row0 = blockIdx.x * 64;
    int l15 = lane & 15, q = lane >> 4;

    floatx4 acc[2] = {};

    for (int k0 = 0; k0 < K; k0 += 32) {
        {
            int flat = t * 8;
            int m = flat >> 5, kk = flat & 31;
            uint4 va = make_uint4(0u, 0u, 0u, 0u);
            int gr = row0 + m;
            if (gr < M) va = *(const uint4*)(A + (size_t)gr * K + k0 + kk);
            *(uint4*)(&As[m * 40 + kk]) = va;
            if (t < 128) {
                int nn = t >> 2, kb = (t & 3) * 8;
                *(uint4*)(&Bs[nn * 40 + kb]) = *(const uint4*)(Bt + (size_t)nn * K + k0 + kb);
            }
        }
        __syncthreads();
        short8 af = *(const short8*)(&As[(w * 16 + l15) * 40 + q * 8]);
        short8 b0 = *(const short8*)(&Bs[(l15) * 40 + q * 8]);
        short8 b1 = *(const short8*)(&Bs[(16 + l15) * 40 + q * 8]);
        acc[0] = __builtin_amdgcn_mfma_f32_16x16x32_bf16(af, b0, acc[0], 0, 0, 0);
        acc[1] = __builtin_amdgcn_mfma_f32_16x16x32_bf16(af, b1, acc[1], 0, 0, 0);
        __syncthreads();
    }

    float as_lo = att_s[l15], as_hi = att_s[16 + l15];
    float ad_lo = att_d[l15], ad_hi = att_d[16 + l15];
    #pragma unroll
    for (int p = 0; p < 4; ++p) {
        int r = row0 + w * 16 + q * 4 + p;
        bool ok = r < M;
        float v0 = acc[0][p], v1 = acc[1][p];
        if (ok) {
            O[(size_t)r * 32 + l15]      = f2bf(v0);
            O[(size_t)r * 32 + 16 + l15] = f2bf(v1);
        }
        float ds = v0 * as_lo + v1 * as_hi;
        float dd = v0 * ad_lo + v1 * ad_hi;
        #pragma unroll
        for (int mk = 1; mk <= 8; mk <<= 1) {
            ds += __shfl_xor(ds, mk);
            dd += __shfl_xor(dd, mk);
        }
        if (ok && l15 == 0) { a_s[r] = ds; a_d[r] = dd; }
    }
}

// ---------------- layer-2: single-pass softmax + aggregation + log-softmax ----------------

__global__ __launch_bounds__(256) void k_l2(const unsigned short* __restrict__ hw2,
                                            const float* __restrict__ a_s,
                                            const float* __restrict__ a_d,
                                            const int* __restrict__ off,
                                            const int* __restrict__ src_s,
                                            const float* __restrict__ bias,
                                            float* __restrict__ outp, int N) {
    int wid = threadIdx.x >> 6, lane = threadIdx.x & 63;
    int n = blockIdx.x * 4 + wid;
    if (n >= N) return;
    int p0 = off[n], p1 = off[n + 1];
    float adv = a_d[n];
    int c = lane & 31, ep = lane >> 5;

    float acc = 0.f, s = 0.f;
    int p = p0;
    for (; p + 64 <= p1; p += 64) {
        int bsrc = src_s[p + lane];
        float e = a_s[bsrc] + adv;
        e = e > 0.f ? e : NEG_SLOPE * e;
        float w64 = __expf(e);
        #pragma unroll
        for (int j = 0; j < 64; j += 2) {
            int sj = __shfl(bsrc, j + ep);
            float wj = __shfl(w64, j + ep);
            s += wj;
            acc = fmaf(wj, bf2f(hw2[(size_t)sj * 32 + c]), acc);
        }
    }
    if (p < p1) {
        int nb = p1 - p;
        int bsrc = src_s[p + (lane < nb ? lane : 0)];
        float e = a_s[bsrc] + adv;
        e = e > 0.f ? e : NEG_SLOPE * e;
        float w64 = __expf(e);
        for (int j = 0; j < nb; j += 2) {
            int idx = j + ep;
            bool valid = idx < nb;
            int idc = valid ? idx : 0;
            int sj = __shfl(bsrc, idc);
            float wj = __shfl(w64, idc);
            if (valid) {
                s += wj;
                acc = fmaf(wj, bf2f(hw2[(size_t)sj * 32 + c]), acc);
            }
        }
    }
    acc += __shfl_xor(acc, 32);
    s   += __shfl_xor(s, 32);
    float v = acc / (s + SM_EPS) + bias[c];
    float mx = v;
    #pragma unroll
    for (int mk = 16; mk >= 1; mk >>= 1) mx = fmaxf(mx, __shfl_xor(mx, mk, 32));
    float ex = __expf(v - mx);
    float sum = ex;
    #pragma unroll
    for (int mk = 16; mk >= 1; mk >>= 1) sum += __shfl_xor(sum, mk, 32);
    if (lane < 32) outp[(size_t)n * 32 + c] = (v - mx) - __logf(sum);
}

// ---------------- launch ----------------

extern "C" void kernel_launch(void* const* d_in, const int* in_sizes, int n_in,
                              void* d_out, int out_size, void* d_ws, size_t ws_size,
                              hipStream_t stream) {
    const float* x   = (const float*)d_in[0];
    const int*   ei  = (const int*)d_in[1];
    const float* W1  = (const float*)d_in[2];
    const float* as1 = (const float*)d_in[3];
    const float* ad1 = (const float*)d_in[4];
    const float* b1  = (const float*)d_in[5];
    const float* W2  = (const float*)d_in[6];
    const float* as2 = (const float*)d_in[7];
    const float* ad2 = (const float*)d_in[8];
    const float* b2  = (const float*)d_in[9];
    float* out = (float*)d_out;

    const int F = 512;
    const int N = in_sizes[0] / F;     // 20000
    const int E = in_sizes[1] / 2;     // 320000
    const int Ep = E + N;              // with self-loops
    const int* srcA = ei;
    const int* dstA = ei + E;

    char* w = (char*)d_ws;
    auto alloc = [&](size_t b) -> void* {
        void* p = (void*)w;
        w += (b + 255) & ~(size_t)255;
        return p;
    };
    unsigned short* xbf  = (unsigned short*)alloc((size_t)N * 512 * 2);
    unsigned short* w1t  = (unsigned short*)alloc((size_t)512 * 512 * 2);
    unsigned short* w2bt = (unsigned short*)alloc((size_t)32 * 512 * 2);
    unsigned short* xw1  = (unsigned short*)alloc((size_t)N * 512 * 2);
    unsigned short* hbuf = (unsigned short*)alloc((size_t)N * 512 * 2);   // bf16 h
    float* a_s1 = (float*)alloc((size_t)N * 8 * 4);   // head-major [8][N]
    float* a_d1 = (float*)alloc((size_t)N * 8 * 4);   // head-major [8][N]
    unsigned short* hw2 = (unsigned short*)alloc((size_t)N * 32 * 2);    // bf16 hw2
    float* a_s2 = (float*)alloc((size_t)N * 4);
    float* a_d2 = (float*)alloc((size_t)N * 4);
    int* deg    = (int*)alloc((size_t)N * 4);
    int* incl   = (int*)alloc((size_t)N * 4);
    int* part   = (int*)alloc(256 * 4);
    int* off    = (int*)alloc((size_t)(N + 1) * 4);
    int* cursor = (int*)alloc((size_t)N * 4);
    int* src_s  = (int*)alloc((size_t)Ep * 4);
    int* bins   = (int*)alloc(64 * 4);
    int* bincur = (int*)alloc(64 * 4);
    int* perm   = (int*)alloc((size_t)N * 4);

    int egrid = (Ep + 255) / 256;
    int sgrid = (N + 255) / 256;
    int ngrid4 = (N + 3) / 4;
    int nblk_x = (N * 512 / 4) / 256;           // 10000
    int nblk_w2 = (32 * 512 + 255) / 256;       // 64

    hipMemsetAsync(deg, 0, (size_t)N * 4, stream);
    hipMemsetAsync(bins, 0, 64 * 4, stream);

    // fused prep: deg | x cast | W1t | W2t
    k_prep<<<egrid + nblk_x + 256 + nblk_w2, 256, 0, stream>>>(
        x, xbf, W1, w1t, W2, w2bt, dstA, E, Ep, deg, egrid, nblk_x);

    // CSR + degree bins
    k_scan1<<<sgrid, 256, 0, stream>>>(deg, incl, part, bins, N);
    k_binscan<<<1, 64, 0, stream>>>(bins, bincur);
    k_scan3<<<sgrid, 256, 0, stream>>>(incl, part, deg, off, cursor, N);
    k_scatter<<<egrid + sgrid, 256, 0, stream>>>(srcA, dstA, E, Ep, cursor, src_s,
                                                 deg, bincur, perm, egrid, N);

    // layer 1
    {
        dim3 g1((N + 127) / 128, 512 / 128);
        k_gemm1_mfma<<<g1, 256, 0, stream>>>(xbf, w1t, as1, ad1, xw1, a_s1, a_d1, N);
    }
    {
        int ngrid32 = (N + 31) / 32;           // node-slot groups of 32
        k_l1<<<ngrid32 * 8, 256, 0, stream>>>(xw1, a_s1, a_d1, off, src_s, perm, b1, hbuf, N);
    }

    // layer 2
    k_gemm2_mfma<<<(N + 63) / 64, 256, 0, stream>>>(hbuf, w2bt, as2, ad2, hw2, a_s2, a_d2, N);
    k_l2<<<ngrid4, 256, 0, stream>>>(hw2, a_s2, a_d2, off, src_s, b2, out, N);
}

// Round 14
// 257.376 us; speedup vs baseline: 1.1857x; 1.1857x over previous
//
#include <hip/hip_runtime.h>
#include <math.h>

#define NEG_SLOPE 0.2f
#define SM_EPS 1e-16f

typedef short short8 __attribute__((ext_vector_type(8)));
typedef float floatx4 __attribute__((ext_vector_type(4)));

// ---------------- helpers ----------------

__device__ inline unsigned short f2bf(float x) {
    unsigned int u = __float_as_uint(x);
    unsigned int r = (u + 0x7FFFu + ((u >> 16) & 1u)) >> 16;
    return (unsigned short)r;
}

__device__ inline float bf2f(unsigned short h) {
    return __uint_as_float(((unsigned int)h) << 16);
}

__device__ inline float bflo(unsigned int u) { return __uint_as_float(u << 16); }
__device__ inline float bfhi(unsigned int u) { return __uint_as_float(u & 0xFFFF0000u); }

// async global->LDS 16B copy: LDS dst = wave-uniform base + lane*16
__device__ __forceinline__ void gl_lds16(const unsigned short* g, unsigned short* l) {
    __builtin_amdgcn_global_load_lds(
        (const __attribute__((address_space(1))) unsigned int*)(g),
        (__attribute__((address_space(3))) unsigned int*)(l), 16, 0, 0);
}

__device__ inline void get_edge(const int* __restrict__ srcA, const int* __restrict__ dstA,
                                int e, int E, int& s, int& d) {
    if (e < E) { s = srcA[e]; d = dstA[e]; }
    else { s = e - E; d = e - E; }   // self-loops appended after real edges
}

// ---------------- fused prep: deg histogram | x->bf16 | W1t | W2t ----------------

__global__ __launch_bounds__(256) void k_prep(const float* __restrict__ x,
                                              unsigned short* __restrict__ xb,
                                              const float* __restrict__ W1,
                                              unsigned short* __restrict__ w1t,
                                              const float* __restrict__ W2,
                                              unsigned short* __restrict__ w2bt,
                                              const int* __restrict__ dstA,
                                              int E, int Ep,
                                              int* __restrict__ deg,
                                              int nblk_deg, int nblk_x) {
    __shared__ float tile[32][33];
    int bx = blockIdx.x;
    int t = threadIdx.x;
    if (bx < nblk_deg) {
        int e = bx * 256 + t;
        if (e < Ep) {
            int d = (e < E) ? dstA[e] : (e - E);
            atomicAdd(&deg[d], 1);
        }
    } else if (bx < nblk_deg + nblk_x) {
        int i = ((bx - nblk_deg) * 256 + t) * 4;
        float4 v = *(const float4*)(x + i);
        ushort4 o;
        o.x = f2bf(v.x); o.y = f2bf(v.y); o.z = f2bf(v.z); o.w = f2bf(v.w);
        *(ushort4*)(xb + i) = o;
    } else if (bx < nblk_deg + nblk_x + 256) {
        int b = bx - nblk_deg - nblk_x;          // 0..255
        int kb = (b & 15) * 32;                  // k base
        int nb = (b >> 4) * 32;                  // n base
        int tx = t & 31, ty = t >> 5;            // 32x8
        #pragma unroll
        for (int i = 0; i < 32; i += 8)
            tile[ty + i][tx] = W1[(size_t)(kb + ty + i) * 512 + nb + tx];
        __syncthreads();
        #pragma unroll
        for (int i = 0; i < 32; i += 8)
            w1t[(size_t)(nb + ty + i) * 512 + kb + tx] = f2bf(tile[tx][ty + i]);
    } else {
        int i = (bx - nblk_deg - nblk_x - 256) * 256 + t;   // 0..16383
        int c = i >> 9, k = i & 511;
        w2bt[i] = f2bf(W2[k * 32 + c]);
    }
}

// ---------------- CSR build + degree-bin histogram ----------------

__global__ __launch_bounds__(256) void k_scan1(const int* __restrict__ deg, int* __restrict__ incl,
                                               int* __restrict__ part, int* __restrict__ bins, int N) {
    __shared__ int sm[256];
    __shared__ int hist[64];
    int t = threadIdx.x;
    if (t < 64) hist[t] = 0;
    int i = blockIdx.x * 256 + t;
    int v = (i < N) ? deg[i] : 0;
    sm[t] = v;
    __syncthreads();
    if (i < N) atomicAdd(&hist[v < 63 ? v : 63], 1);
    for (int o = 1; o < 256; o <<= 1) {
        int x = (t >= o) ? sm[t - o] : 0;
        __syncthreads();
        sm[t] += x;
        __syncthreads();
    }
    if (i < N) incl[i] = sm[t];
    if (t == 255) part[blockIdx.x] = sm[255];
    __syncthreads();
    if (t < 64 && hist[t]) atomicAdd(&bins[t], hist[t]);
}

// exclusive prefix over the 64 degree bins -> bin cursors
__global__ void k_binscan(const int* __restrict__ bins, int* __restrict__ bincur) {
    if (threadIdx.x == 0) {
        int run = 0;
        for (int i = 0; i < 64; ++i) { bincur[i] = run; run += bins[i]; }
    }
}

// degree-binned node permutation, contention-free:
// LDS per-bin count (LDS atomics) -> ONE global atomic per (block,bin) -> write.
__global__ __launch_bounds__(256) void k_perm(const int* __restrict__ deg,
                                              int* __restrict__ bincur,
                                              int* __restrict__ perm, int N) {
    __shared__ int cnt[64];
    __shared__ int base[64];
    int t = threadIdx.x;
    int i = blockIdx.x * 256 + t;
    if (t < 64) cnt[t] = 0;
    __syncthreads();
    int b = 0, local = 0;
    bool ok = i < N;
    if (ok) {
        b = deg[i]; b = b < 63 ? b : 63;
        local = atomicAdd(&cnt[b], 1);
    }
    __syncthreads();
    if (t < 64 && cnt[t]) base[t] = atomicAdd(&bincur[t], cnt[t]);
    __syncthreads();
    if (ok) perm[base[b] + local] = i;
}

// scan3 with inlined partial-prefix
__global__ __launch_bounds__(256) void k_scan3(const int* __restrict__ incl, const int* __restrict__ part,
                                               const int* __restrict__ deg, int* __restrict__ off,
                                               int* __restrict__ cursor, int N) {
    __shared__ int sm[256];
    int bx = blockIdx.x, t = threadIdx.x;
    int partial = 0;
    for (int i = t; i < bx; i += 256) partial += part[i];
    sm[t] = partial; __syncthreads();
    for (int o = 128; o > 0; o >>= 1) {
        if (t < o) sm[t] += sm[t + o];
        __syncthreads();
    }
    int base = sm[0];
    int i = bx * 256 + t;
    if (i >= N) return;
    int v = incl[i] + base;   // inclusive scan value
    off[i + 1] = v;
    cursor[i] = v - deg[i];
    if (i == 0) off[0] = 0;
}

// edge scatter (round-12 form)
__global__ __launch_bounds__(256) void k_scatter(const int* __restrict__ srcA, const int* __restrict__ dstA,
                                                 int E, int Ep, int* __restrict__ cursor,
                                                 int* __restrict__ src_s) {
    int e = blockIdx.x * 256 + threadIdx.x;
    if (e >= Ep) return;
    int s, d; get_edge(srcA, dstA, e, E, s, d);
    int p = atomicAdd(&cursor[d], 1);
    src_s[p] = s;
}

// ---------------- GEMM1 (bf16 MFMA, global_load_lds staging) + fused attn1 ----------------
// attn dots stored HEAD-MAJOR: a_sd[h*N + r], a_dd[h*N + r].

__global__ __launch_bounds__(256) void k_gemm1_mfma(const unsigned short* __restrict__ A,
                                                    const unsigned short* __restrict__ Bt,
                                                    const float* __restrict__ att_s,
                                                    const float* __restrict__ att_d,
                                                    unsigned short* __restrict__ C,
                                                    float* __restrict__ a_sd,
                                                    float* __restrict__ a_dd, int M) {
    const int K = 512;
    __shared__ unsigned short As[128 * 32];
    __shared__ unsigned short Bs[128 * 32];
    int t = threadIdx.x;
    int lane = t & 63;
    int w = t >> 6;
    int row0 = blockIdx.x * 128;
    int col0 = blockIdx.y * 128;
    int wm = (w >> 1) * 64, wn = (w & 1) * 64;
    int l15 = lane & 15, q = lane >> 4;

    int mrow = t >> 2;            // 0..63
    int kk = (t & 3) * 8;
    unsigned short* ldsA0 = &As[w * 512];
    unsigned short* ldsA1 = &As[2048 + w * 512];
    unsigned short* ldsB0 = &Bs[w * 512];
    unsigned short* ldsB1 = &Bs[2048 + w * 512];

    floatx4 acc[4][4] = {};

    for (int k0 = 0; k0 < K; k0 += 32) {
        gl_lds16(A  + (size_t)(row0 + mrow) * K + k0 + kk,      ldsA0);
        gl_lds16(A  + (size_t)(row0 + 64 + mrow) * K + k0 + kk, ldsA1);
        gl_lds16(Bt + (size_t)(col0 + mrow) * K + k0 + kk,      ldsB0);
        gl_lds16(Bt + (size_t)(col0 + 64 + mrow) * K + k0 + kk, ldsB1);
        __syncthreads();
        short8 af[4], bfr[4];
        #pragma unroll
        for (int i = 0; i < 4; ++i)
            af[i] = *(const short8*)(&As[(wm + i * 16 + l15) * 32 + q * 8]);
        #pragma unroll
        for (int j = 0; j < 4; ++j)
            bfr[j] = *(const short8*)(&Bs[(wn + j * 16 + l15) * 32 + q * 8]);
        #pragma unroll
        for (int i = 0; i < 4; ++i)
            #pragma unroll
            for (int j = 0; j < 4; ++j)
                acc[i][j] = __builtin_amdgcn_mfma_f32_16x16x32_bf16(af[i], bfr[j], acc[i][j], 0, 0, 0);
        __syncthreads();
    }

    #pragma unroll
    for (int i = 0; i < 4; ++i) {
        #pragma unroll
        for (int p = 0; p < 4; ++p) {
            int r = row0 + wm + i * 16 + q * 4 + p;
            if (r < M) {
                #pragma unroll
                for (int j = 0; j < 4; ++j) {
                    int c = col0 + wn + j * 16 + l15;
                    C[(size_t)r * 512 + c] = f2bf(acc[i][j][p]);
                }
            }
        }
    }

    int hh = blockIdx.y * 2 + (w & 1);
    float asr[4], adr[4];
    #pragma unroll
    for (int j = 0; j < 4; ++j) {
        asr[j] = att_s[hh * 64 + j * 16 + l15];
        adr[j] = att_d[hh * 64 + j * 16 + l15];
    }
    #pragma unroll
    for (int i = 0; i < 4; ++i) {
        #pragma unroll
        for (int p = 0; p < 4; ++p) {
            float ds = 0.f, dd = 0.f;
            #pragma unroll
            for (int j = 0; j < 4; ++j) {
                ds = fmaf(acc[i][j][p], asr[j], ds);
                dd = fmaf(acc[i][j][p], adr[j], dd);
            }
            #pragma unroll
            for (int mk = 1; mk <= 8; mk <<= 1) {
                ds += __shfl_xor(ds, mk);
                dd += __shfl_xor(dd, mk);
            }
            int r = row0 + wm + i * 16 + q * 4 + p;
            if (l15 == 0 && r < M) {
                a_sd[(size_t)hh * M + r] = ds;
                a_dd[(size_t)hh * M + r] = dd;
            }
        }
    }
}

// ---------------- layer-1: head-sliced, lane-private, degree-binned ----------------
// Wave = 8 nodes x 1 head via perm[] (degree-grouped -> near-equal degrees per wave).
// head = blockIdx.x & 7 -> XCD affinity. Zero cross-lane ops.

__global__ __launch_bounds__(256) void k_l1(const unsigned short* __restrict__ xw,
                                            const float* __restrict__ a_s,
                                            const float* __restrict__ a_d,
                                            const int* __restrict__ off,
                                            const int* __restrict__ src_s,
                                            const int* __restrict__ perm,
                                            const float* __restrict__ bias,
                                            unsigned short* __restrict__ hout, int N) {
    int wid = threadIdx.x >> 6, lane = threadIdx.x & 63;
    int h = blockIdx.x & 7;
    int slot = (blockIdx.x >> 3) * 32 + wid * 8 + (lane >> 3);
    int li = lane & 7;
    if (slot >= N) return;
    int n = perm[slot];
    int p0 = off[n], p1 = off[n + 1];
    const float* ash = a_s + (size_t)h * N;
    float adv = a_d[(size_t)h * N + n];
    const size_t cbase = (size_t)h * 64 + (size_t)li * 8;

    float acc[8] = {};
    float s = 0.f;
    int p = p0;
    for (; p + 2 <= p1; p += 2) {
        int s0 = src_s[p];
        int s1 = src_s[p + 1];
        const uint4 u0 = *(const uint4*)(xw + (size_t)s0 * 512 + cbase);
        const uint4 u1 = *(const uint4*)(xw + (size_t)s1 * 512 + cbase);
        float e0 = ash[s0] + adv; e0 = e0 > 0.f ? e0 : NEG_SLOPE * e0;
        float e1 = ash[s1] + adv; e1 = e1 > 0.f ? e1 : NEG_SLOPE * e1;
        float w0 = __expf(e0);
        float w1 = __expf(e1);
        s += w0 + w1;
        acc[0] = fmaf(w0, bflo(u0.x), acc[0]); acc[1] = fmaf(w0, bfhi(u0.x), acc[1]);
        acc[2] = fmaf(w0, bflo(u0.y), acc[2]); acc[3] = fmaf(w0, bfhi(u0.y), acc[3]);
        acc[4] = fmaf(w0, bflo(u0.z), acc[4]); acc[5] = fmaf(w0, bfhi(u0.z), acc[5]);
        acc[6] = fmaf(w0, bflo(u0.w), acc[6]); acc[7] = fmaf(w0, bfhi(u0.w), acc[7]);
        acc[0] = fmaf(w1, bflo(u1.x), acc[0]); acc[1] = fmaf(w1, bfhi(u1.x), acc[1]);
        acc[2] = fmaf(w1, bflo(u1.y), acc[2]); acc[3] = fmaf(w1, bfhi(u1.y), acc[3]);
        acc[4] = fmaf(w1, bflo(u1.z), acc[4]); acc[5] = fmaf(w1, bfhi(u1.z), acc[5]);
        acc[6] = fmaf(w1, bflo(u1.w), acc[6]); acc[7] = fmaf(w1, bfhi(u1.w), acc[7]);
    }
    if (p < p1) {
        int s0 = src_s[p];
        const uint4 u0 = *(const uint4*)(xw + (size_t)s0 * 512 + cbase);
        float e0 = ash[s0] + adv; e0 = e0 > 0.f ? e0 : NEG_SLOPE * e0;
        float w0 = __expf(e0);
        s += w0;
        acc[0] = fmaf(w0, bflo(u0.x), acc[0]); acc[1] = fmaf(w0, bfhi(u0.x), acc[1]);
        acc[2] = fmaf(w0, bflo(u0.y), acc[2]); acc[3] = fmaf(w0, bfhi(u0.y), acc[3]);
        acc[4] = fmaf(w0, bflo(u0.z), acc[4]); acc[5] = fmaf(w0, bfhi(u0.z), acc[5]);
        acc[6] = fmaf(w0, bflo(u0.w), acc[6]); acc[7] = fmaf(w0, bfhi(u0.w), acc[7]);
    }

    float inv = 1.f / (s + SM_EPS);
    unsigned int ov[4];
    #pragma unroll
    for (int j = 0; j < 4; ++j) {
        float v0 = acc[2 * j] * inv     + bias[cbase + 2 * j];
        float v1 = acc[2 * j + 1] * inv + bias[cbase + 2 * j + 1];
        v0 = v0 > 0.f ? v0 : __expf(v0) - 1.f;
        v1 = v1 > 0.f ? v1 : __expf(v1) - 1.f;
        ov[j] = (unsigned int)f2bf(v0) | ((unsigned int)f2bf(v1) << 16);
    }
    *(uint4*)(hout + (size_t)n * 512 + cbase) = make_uint4(ov[0], ov[1], ov[2], ov[3]);
}

// ---------------- GEMM2 (bf16 MFMA) + fused attn2; hw2 stored bf16 ----------------

__global__ __launch_bounds__(256) void k_gemm2_mfma(const unsigned short* __restrict__ A,
                                                    const unsigned short* __restrict__ Bt,
                                                    const float* __restrict__ att_s,
                                                    const float* __restrict__ att_d,
                                                    unsigned short* __restrict__ O,
                                                    float* __restrict__ a_s, float* __restrict__ a_d,
                                                    int M) {
    const int K = 512;
    __shared__ unsigned short As[64 * 40];
    __shared__ unsigned short Bs[32 * 40];
    int t = threadIdx.x;
    int lane = t & 63;
    int w = t >> 6;
    int row0 = blockIdx.x * 64;
    int l15 = lane & 15, q = lane >> 4;

    floatx4 acc[2] = {};

    for (int k0 = 0; k0 < K; k0 += 32) {
        {
            int flat = t * 8;
            int m = flat >> 5, kk = flat & 31;
            uint4 va = make_uint4(0u, 0u, 0u, 0u);
            int gr = row0 + m;
            if (gr < M) va = *(const uint4*)(A + (size_t)gr * K + k0 + kk);
            *(uint4*)(&As[m * 40 + kk]) = va;
            if (t < 128) {
                int nn = t >> 2, kb = (t & 3) * 8;
                *(uint4*)(&Bs[nn * 40 + kb]) = *(const uint4*)(Bt + (size_t)nn * K + k0 + kb);
            }
        }
        __syncthreads();
        short8 af = *(const short8*)(&As[(w * 16 + l15) * 40 + q * 8]);
        short8 b0 = *(const short8*)(&Bs[(l15) * 40 + q * 8]);
        short8 b1 = *(const short8*)(&Bs[(16 + l15) * 40 + q * 8]);
        acc[0] = __builtin_amdgcn_mfma_f32_16x16x32_bf16(af, b0, acc[0], 0, 0, 0);
        acc[1] = __builtin_amdgcn_mfma_f32_16x16x32_bf16(af, b1, acc[1], 0, 0, 0);
        __syncthreads();
    }

    float as_lo = att_s[l15], as_hi = att_s[16 + l15];
    float ad_lo = att_d[l15], ad_hi = att_d[16 + l15];
    #pragma unroll
    for (int p = 0; p < 4; ++p) {
        int r = row0 + w * 16 + q * 4 + p;
        bool ok = r < M;
        float v0 = acc[0][p], v1 = acc[1][p];
        if (ok) {
            O[(size_t)r * 32 + l15]      = f2bf(v0);
            O[(size_t)r * 32 + 16 + l15] = f2bf(v1);
        }
        float ds = v0 * as_lo + v1 * as_hi;
        float dd = v0 * ad_lo + v1 * ad_hi;
        #pragma unroll
        for (int mk = 1; mk <= 8; mk <<= 1) {
            ds += __shfl_xor(ds, mk);
            dd += __shfl_xor(dd, mk);
        }
        if (ok && l15 == 0) { a_s[r] = ds; a_d[r] = dd; }
    }
}

// ---------------- layer-2: single-pass softmax + aggregation + log-softmax ----------------

__global__ __launch_bounds__(256) void k_l2(const unsigned short* __restrict__ hw2,
                                            const float* __restrict__ a_s,
                                            const float* __restrict__ a_d,
                                            const int* __restrict__ off,
                                            const int* __restrict__ src_s,
                                            const float* __restrict__ bias,
                                            float* __restrict__ outp, int N) {
    int wid = threadIdx.x >> 6, lane = threadIdx.x & 63;
    int n = blockIdx.x * 4 + wid;
    if (n >= N) return;
    int p0 = off[n], p1 = off[n + 1];
    float adv = a_d[n];
    int c = lane & 31, ep = lane >> 5;

    float acc = 0.f, s = 0.f;
    int p = p0;
    for (; p + 64 <= p1; p += 64) {
        int bsrc = src_s[p + lane];
        float e = a_s[bsrc] + adv;
        e = e > 0.f ? e : NEG_SLOPE * e;
        float w64 = __expf(e);
        #pragma unroll
        for (int j = 0; j < 64; j += 2) {
            int sj = __shfl(bsrc, j + ep);
            float wj = __shfl(w64, j + ep);
            s += wj;
            acc = fmaf(wj, bf2f(hw2[(size_t)sj * 32 + c]), acc);
        }
    }
    if (p < p1) {
        int nb = p1 - p;
        int bsrc = src_s[p + (lane < nb ? lane : 0)];
        float e = a_s[bsrc] + adv;
        e = e > 0.f ? e : NEG_SLOPE * e;
        float w64 = __expf(e);
        for (int j = 0; j < nb; j += 2) {
            int idx = j + ep;
            bool valid = idx < nb;
            int idc = valid ? idx : 0;
            int sj = __shfl(bsrc, idc);
            float wj = __shfl(w64, idc);
            if (valid) {
                s += wj;
                acc = fmaf(wj, bf2f(hw2[(size_t)sj * 32 + c]), acc);
            }
        }
    }
    acc += __shfl_xor(acc, 32);
    s   += __shfl_xor(s, 32);
    float v = acc / (s + SM_EPS) + bias[c];
    float mx = v;
    #pragma unroll
    for (int mk = 16; mk >= 1; mk >>= 1) mx = fmaxf(mx, __shfl_xor(mx, mk, 32));
    float ex = __expf(v - mx);
    float sum = ex;
    #pragma unroll
    for (int mk = 16; mk >= 1; mk >>= 1) sum += __shfl_xor(sum, mk, 32);
    if (lane < 32) outp[(size_t)n * 32 + c] = (v - mx) - __logf(sum);
}

// ---------------- launch ----------------

extern "C" void kernel_launch(void* const* d_in, const int* in_sizes, int n_in,
                              void* d_out, int out_size, void* d_ws, size_t ws_size,
                              hipStream_t stream) {
    const float* x   = (const float*)d_in[0];
    const int*   ei  = (const int*)d_in[1];
    const float* W1  = (const float*)d_in[2];
    const float* as1 = (const float*)d_in[3];
    const float* ad1 = (const float*)d_in[4];
    const float* b1  = (const float*)d_in[5];
    const float* W2  = (const float*)d_in[6];
    const float* as2 = (const float*)d_in[7];
    const float* ad2 = (const float*)d_in[8];
    const float* b2  = (const float*)d_in[9];
    float* out = (float*)d_out;

    const int F = 512;
    const int N = in_sizes[0] / F;     // 20000
    const int E = in_sizes[1] / 2;     // 320000
    const int Ep = E + N;              // with self-loops
    const int* srcA = ei;
    const int* dstA = ei + E;

    char* w = (char*)d_ws;
    auto alloc = [&](size_t b) -> void* {
        void* p = (void*)w;
        w += (b + 255) & ~(size_t)255;
        return p;
    };
    unsigned short* xbf  = (unsigned short*)alloc((size_t)N * 512 * 2);
    unsigned short* w1t  = (unsigned short*)alloc((size_t)512 * 512 * 2);
    unsigned short* w2bt = (unsigned short*)alloc((size_t)32 * 512 * 2);
    unsigned short* xw1  = (unsigned short*)alloc((size_t)N * 512 * 2);
    unsigned short* hbuf = (unsigned short*)alloc((size_t)N * 512 * 2);   // bf16 h
    float* a_s1 = (float*)alloc((size_t)N * 8 * 4);   // head-major [8][N]
    float* a_d1 = (float*)alloc((size_t)N * 8 * 4);   // head-major [8][N]
    unsigned short* hw2 = (unsigned short*)alloc((size_t)N * 32 * 2);    // bf16 hw2
    float* a_s2 = (float*)alloc((size_t)N * 4);
    float* a_d2 = (float*)alloc((size_t)N * 4);
    int* deg    = (int*)alloc((size_t)N * 4);
    int* incl   = (int*)alloc((size_t)N * 4);
    int* part   = (int*)alloc(256 * 4);
    int* off    = (int*)alloc((size_t)(N + 1) * 4);
    int* cursor = (int*)alloc((size_t)N * 4);
    int* src_s  = (int*)alloc((size_t)Ep * 4);
    int* bins   = (int*)alloc(64 * 4);
    int* bincur = (int*)alloc(64 * 4);
    int* perm   = (int*)alloc((size_t)N * 4);

    int egrid = (Ep + 255) / 256;
    int sgrid = (N + 255) / 256;
    int ngrid4 = (N + 3) / 4;
    int nblk_x = (N * 512 / 4) / 256;           // 10000
    int nblk_w2 = (32 * 512 + 255) / 256;       // 64

    hipMemsetAsync(deg, 0, (size_t)N * 4, stream);
    hipMemsetAsync(bins, 0, 64 * 4, stream);

    // fused prep: deg | x cast | W1t | W2t
    k_prep<<<egrid + nblk_x + 256 + nblk_w2, 256, 0, stream>>>(
        x, xbf, W1, w1t, W2, w2bt, dstA, E, Ep, deg, egrid, nblk_x);

    // CSR + degree-binned permutation (contention-free)
    k_scan1<<<sgrid, 256, 0, stream>>>(deg, incl, part, bins, N);
    k_binscan<<<1, 64, 0, stream>>>(bins, bincur);
    k_perm<<<sgrid, 256, 0, stream>>>(deg, bincur, perm, N);
    k_scan3<<<sgrid, 256, 0, stream>>>(incl, part, deg, off, cursor, N);
    k_scatter<<<egrid, 256, 0, stream>>>(srcA, dstA, E, Ep, cursor, src_s);

    // layer 1
    {
        dim3 g1((N + 127) / 128, 512 / 128);
        k_gemm1_mfma<<<g1, 256, 0, stream>>>(xbf, w1t, as1, ad1, xw1, a_s1, a_d1, N);
    }
    {
        int ngrid32 = (N + 31) / 32;           // node-slot groups of 32
        k_l1<<<ngrid32 * 8, 256, 0, stream>>>(xw1, a_s1, a_d1, off, src_s, perm, b1, hbuf, N);
    }

    // layer 2
    k_gemm2_mfma<<<(N + 63) / 64, 256, 0, stream>>>(hbuf, w2bt, as2, ad2, hw2, a_s2, a_d2, N);
    k_l2<<<ngrid4, 256, 0, stream>>>(hw2, a_s2, a_d2, off, src_s, b2, out, N);
}

// Round 15
// 244.190 us; speedup vs baseline: 1.2497x; 1.0540x over previous
//
#include <hip/hip_runtime.h>
#include <math.h>

#define NEG_SLOPE 0.2f
#define SM_EPS 1e-16f

typedef short short8 __attribute__((ext_vector_type(8)));
typedef float floatx4 __attribute__((ext_vector_type(4)));

// ---------------- helpers ----------------

__device__ inline unsigned short f2bf(float x) {
    unsigned int u = __float_as_uint(x);
    unsigned int r = (u + 0x7FFFu + ((u >> 16) & 1u)) >> 16;
    return (unsigned short)r;
}

__device__ inline float bf2f(unsigned short h) {
    return __uint_as_float(((unsigned int)h) << 16);
}

__device__ inline float bflo(unsigned int u) { return __uint_as_float(u << 16); }
__device__ inline float bfhi(unsigned int u) { return __uint_as_float(u & 0xFFFF0000u); }

// async global->LDS 16B copy: LDS dst = wave-uniform base + lane*16
__device__ __forceinline__ void gl_lds16(const unsigned short* g, unsigned short* l) {
    __builtin_amdgcn_global_load_lds(
        (const __attribute__((address_space(1))) unsigned int*)(g),
        (__attribute__((address_space(3))) unsigned int*)(l), 16, 0, 0);
}

__device__ inline void get_edge(const int* __restrict__ srcA, const int* __restrict__ dstA,
                                int e, int E, int& s, int& d) {
    if (e < E) { s = srcA[e]; d = dstA[e]; }
    else { s = e - E; d = e - E; }   // self-loops appended after real edges
}

// ---------------- fused prep: deg histogram | x->bf16 | W1t | W2t ----------------

__global__ __launch_bounds__(256) void k_prep(const float* __restrict__ x,
                                              unsigned short* __restrict__ xb,
                                              const float* __restrict__ W1,
                                              unsigned short* __restrict__ w1t,
                                              const float* __restrict__ W2,
                                              unsigned short* __restrict__ w2bt,
                                              const int* __restrict__ dstA,
                                              int E, int Ep,
                                              int* __restrict__ deg,
                                              int nblk_deg, int nblk_x) {
    __shared__ float tile[32][33];
    int bx = blockIdx.x;
    int t = threadIdx.x;
    if (bx < nblk_deg) {
        int e = bx * 256 + t;
        if (e < Ep) {
            int d = (e < E) ? dstA[e] : (e - E);
            atomicAdd(&deg[d], 1);
        }
    } else if (bx < nblk_deg + nblk_x) {
        int i = ((bx - nblk_deg) * 256 + t) * 4;
        float4 v = *(const float4*)(x + i);
        ushort4 o;
        o.x = f2bf(v.x); o.y = f2bf(v.y); o.z = f2bf(v.z); o.w = f2bf(v.w);
        *(ushort4*)(xb + i) = o;
    } else if (bx < nblk_deg + nblk_x + 256) {
        int b = bx - nblk_deg - nblk_x;          // 0..255
        int kb = (b & 15) * 32;                  // k base
        int nb = (b >> 4) * 32;                  // n base
        int tx = t & 31, ty = t >> 5;            // 32x8
        #pragma unroll
        for (int i = 0; i < 32; i += 8)
            tile[ty + i][tx] = W1[(size_t)(kb + ty + i) * 512 + nb + tx];
        __syncthreads();
        #pragma unroll
        for (int i = 0; i < 32; i += 8)
            w1t[(size_t)(nb + ty + i) * 512 + kb + tx] = f2bf(tile[tx][ty + i]);
    } else {
        int i = (bx - nblk_deg - nblk_x - 256) * 256 + t;   // 0..16383
        int c = i >> 9, k = i & 511;
        w2bt[i] = f2bf(W2[k * 32 + c]);
    }
}

// ---------------- CSR build ----------------

__global__ __launch_bounds__(256) void k_scan1(const int* __restrict__ deg, int* __restrict__ incl,
                                               int* __restrict__ part, int N) {
    __shared__ int sm[256];
    int t = threadIdx.x;
    int i = blockIdx.x * 256 + t;
    int v = (i < N) ? deg[i] : 0;
    sm[t] = v; __syncthreads();
    for (int o = 1; o < 256; o <<= 1) {
        int x = (t >= o) ? sm[t - o] : 0;
        __syncthreads();
        sm[t] += x;
        __syncthreads();
    }
    if (i < N) incl[i] = sm[t];
    if (t == 255) part[blockIdx.x] = sm[255];
}

// scan3 with inlined partial-prefix
__global__ __launch_bounds__(256) void k_scan3(const int* __restrict__ incl, const int* __restrict__ part,
                                               const int* __restrict__ deg, int* __restrict__ off,
                                               int* __restrict__ cursor, int N) {
    __shared__ int sm[256];
    int bx = blockIdx.x, t = threadIdx.x;
    int partial = 0;
    for (int i = t; i < bx; i += 256) partial += part[i];
    sm[t] = partial; __syncthreads();
    for (int o = 128; o > 0; o >>= 1) {
        if (t < o) sm[t] += sm[t + o];
        __syncthreads();
    }
    int base = sm[0];
    int i = bx * 256 + t;
    if (i >= N) return;
    int v = incl[i] + base;   // inclusive scan value
    off[i + 1] = v;
    cursor[i] = v - deg[i];
    if (i == 0) off[0] = 0;
}

__global__ __launch_bounds__(256) void k_scatter(const int* __restrict__ srcA, const int* __restrict__ dstA,
                                                 int E, int Ep, int* __restrict__ cursor,
                                                 int* __restrict__ src_s) {
    int e = blockIdx.x * 256 + threadIdx.x;
    if (e >= Ep) return;
    int s, d; get_edge(srcA, dstA, e, E, s, d);
    int p = atomicAdd(&cursor[d], 1);
    src_s[p] = s;
}

// ---------------- GEMM1 (bf16 MFMA, global_load_lds staging) + fused attn1 ----------------
// attn dots stored HEAD-MAJOR: a_sd[h*N + r], a_dd[h*N + r].

__global__ __launch_bounds__(256) void k_gemm1_mfma(const unsigned short* __restrict__ A,
                                                    const unsigned short* __restrict__ Bt,
                                                    const float* __restrict__ att_s,
                                                    const float* __restrict__ att_d,
                                                    unsigned short* __restrict__ C,
                                                    float* __restrict__ a_sd,
                                                    float* __restrict__ a_dd, int M) {
    const int K = 512;
    __shared__ unsigned short As[128 * 32];
    __shared__ unsigned short Bs[128 * 32];
    int t = threadIdx.x;
    int lane = t & 63;
    int w = t >> 6;
    int row0 = blockIdx.x * 128;
    int col0 = blockIdx.y * 128;
    int wm = (w >> 1) * 64, wn = (w & 1) * 64;
    int l15 = lane & 15, q = lane >> 4;

    int mrow = t >> 2;            // 0..63
    int kk = (t & 3) * 8;
    unsigned short* ldsA0 = &As[w * 512];
    unsigned short* ldsA1 = &As[2048 + w * 512];
    unsigned short* ldsB0 = &Bs[w * 512];
    unsigned short* ldsB1 = &Bs[2048 + w * 512];

    floatx4 acc[4][4] = {};

    for (int k0 = 0; k0 < K; k0 += 32) {
        gl_lds16(A  + (size_t)(row0 + mrow) * K + k0 + kk,      ldsA0);
        gl_lds16(A  + (size_t)(row0 + 64 + mrow) * K + k0 + kk, ldsA1);
        gl_lds16(Bt + (size_t)(col0 + mrow) * K + k0 + kk,      ldsB0);
        gl_lds16(Bt + (size_t)(col0 + 64 + mrow) * K + k0 + kk, ldsB1);
        __syncthreads();
        short8 af[4], bfr[4];
        #pragma unroll
        for (int i = 0; i < 4; ++i)
            af[i] = *(const short8*)(&As[(wm + i * 16 + l15) * 32 + q * 8]);
        #pragma unroll
        for (int j = 0; j < 4; ++j)
            bfr[j] = *(const short8*)(&Bs[(wn + j * 16 + l15) * 32 + q * 8]);
        #pragma unroll
        for (int i = 0; i < 4; ++i)
            #pragma unroll
            for (int j = 0; j < 4; ++j)
                acc[i][j] = __builtin_amdgcn_mfma_f32_16x16x32_bf16(af[i], bfr[j], acc[i][j], 0, 0, 0);
        __syncthreads();
    }

    #pragma unroll
    for (int i = 0; i < 4; ++i) {
        #pragma unroll
        for (int p = 0; p < 4; ++p) {
            int r = row0 + wm + i * 16 + q * 4 + p;
            if (r < M) {
                #pragma unroll
                for (int j = 0; j < 4; ++j) {
                    int c = col0 + wn + j * 16 + l15;
                    C[(size_t)r * 512 + c] = f2bf(acc[i][j][p]);
                }
            }
        }
    }

    int hh = blockIdx.y * 2 + (w & 1);
    float asr[4], adr[4];
    #pragma unroll
    for (int j = 0; j < 4; ++j) {
        asr[j] = att_s[hh * 64 + j * 16 + l15];
        adr[j] = att_d[hh * 64 + j * 16 + l15];
    }
    #pragma unroll
    for (int i = 0; i < 4; ++i) {
        #pragma unroll
        for (int p = 0; p < 4; ++p) {
            float ds = 0.f, dd = 0.f;
            #pragma unroll
            for (int j = 0; j < 4; ++j) {
                ds = fmaf(acc[i][j][p], asr[j], ds);
                dd = fmaf(acc[i][j][p], adr[j], dd);
            }
            #pragma unroll
            for (int mk = 1; mk <= 8; mk <<= 1) {
                ds += __shfl_xor(ds, mk);
                dd += __shfl_xor(dd, mk);
            }
            int r = row0 + wm + i * 16 + q * 4 + p;
            if (l15 == 0 && r < M) {
                a_sd[(size_t)hh * M + r] = ds;
                a_dd[(size_t)hh * M + r] = dd;
            }
        }
    }
}

// ---------------- layer-1: head-sliced, lane-private (round-12) + 4-edge ILP unroll ----------------
// Wave = 8 nodes x 1 head; lane = (node-sub = lane>>3, chan-sub li = lane&7).
// head = blockIdx.x & 7 -> XCD affinity (per-XCD xw slice 2.56 MB; (node,head) slice
// = one 128 B line). Lane walks ITS node's edges privately; 4 gathers in flight.

__global__ __launch_bounds__(256) void k_l1(const unsigned short* __restrict__ xw,
                                            const float* __restrict__ a_s,
                                            const float* __restrict__ a_d,
                                            const int* __restrict__ off,
                                            const int* __restrict__ src_s,
                                            const float* __restrict__ bias,
                                            unsigned short* __restrict__ hout, int N) {
    int wid = threadIdx.x >> 6, lane = threadIdx.x & 63;
    int h = blockIdx.x & 7;
    int n = (blockIdx.x >> 3) * 32 + wid * 8 + (lane >> 3);
    int li = lane & 7;
    if (n >= N) return;
    int p0 = off[n], p1 = off[n + 1];
    const float* ash = a_s + (size_t)h * N;
    float adv = a_d[(size_t)h * N + n];
    const size_t cbase = (size_t)h * 64 + (size_t)li * 8;

    float acc[8] = {};
    float s = 0.f;
    int p = p0;
    for (; p + 4 <= p1; p += 4) {
        int s0 = src_s[p];
        int s1 = src_s[p + 1];
        int s2 = src_s[p + 2];
        int s3 = src_s[p + 3];
        const uint4 u0 = *(const uint4*)(xw + (size_t)s0 * 512 + cbase);
        const uint4 u1 = *(const uint4*)(xw + (size_t)s1 * 512 + cbase);
        const uint4 u2 = *(const uint4*)(xw + (size_t)s2 * 512 + cbase);
        const uint4 u3 = *(const uint4*)(xw + (size_t)s3 * 512 + cbase);
        float e0 = ash[s0] + adv; e0 = e0 > 0.f ? e0 : NEG_SLOPE * e0;
        float e1 = ash[s1] + adv; e1 = e1 > 0.f ? e1 : NEG_SLOPE * e1;
        float e2 = ash[s2] + adv; e2 = e2 > 0.f ? e2 : NEG_SLOPE * e2;
        float e3 = ash[s3] + adv; e3 = e3 > 0.f ? e3 : NEG_SLOPE * e3;
        float w0 = __expf(e0);
        float w1 = __expf(e1);
        float w2 = __expf(e2);
        float w3 = __expf(e3);
        s += (w0 + w1) + (w2 + w3);
        acc[0] = fmaf(w0, bflo(u0.x), acc[0]); acc[1] = fmaf(w0, bfhi(u0.x), acc[1]);
        acc[2] = fmaf(w0, bflo(u0.y), acc[2]); acc[3] = fmaf(w0, bfhi(u0.y), acc[3]);
        acc[4] = fmaf(w0, bflo(u0.z), acc[4]); acc[5] = fmaf(w0, bfhi(u0.z), acc[5]);
        acc[6] = fmaf(w0, bflo(u0.w), acc[6]); acc[7] = fmaf(w0, bfhi(u0.w), acc[7]);
        acc[0] = fmaf(w1, bflo(u1.x), acc[0]); acc[1] = fmaf(w1, bfhi(u1.x), acc[1]);
        acc[2] = fmaf(w1, bflo(u1.y), acc[2]); acc[3] = fmaf(w1, bfhi(u1.y), acc[3]);
        acc[4] = fmaf(w1, bflo(u1.z), acc[4]); acc[5] = fmaf(w1, bfhi(u1.z), acc[5]);
        acc[6] = fmaf(w1, bflo(u1.w), acc[6]); acc[7] = fmaf(w1, bfhi(u1.w), acc[7]);
        acc[0] = fmaf(w2, bflo(u2.x), acc[0]); acc[1] = fmaf(w2, bfhi(u2.x), acc[1]);
        acc[2] = fmaf(w2, bflo(u2.y), acc[2]); acc[3] = fmaf(w2, bfhi(u2.y), acc[3]);
        acc[4] = fmaf(w2, bflo(u2.z), acc[4]); acc[5] = fmaf(w2, bfhi(u2.z), acc[5]);
        acc[6] = fmaf(w2, bflo(u2.w), acc[6]); acc[7] = fmaf(w2, bfhi(u2.w), acc[7]);
        acc[0] = fmaf(w3, bflo(u3.x), acc[0]); acc[1] = fmaf(w3, bfhi(u3.x), acc[1]);
        acc[2] = fmaf(w3, bflo(u3.y), acc[2]); acc[3] = fmaf(w3, bfhi(u3.y), acc[3]);
        acc[4] = fmaf(w3, bflo(u3.z), acc[4]); acc[5] = fmaf(w3, bfhi(u3.z), acc[5]);
        acc[6] = fmaf(w3, bflo(u3.w), acc[6]); acc[7] = fmaf(w3, bfhi(u3.w), acc[7]);
    }
    for (; p < p1; ++p) {
        int s0 = src_s[p];
        const uint4 u0 = *(const uint4*)(xw + (size_t)s0 * 512 + cbase);
        float e0 = ash[s0] + adv; e0 = e0 > 0.f ? e0 : NEG_SLOPE * e0;
        float w0 = __expf(e0);
        s += w0;
        acc[0] = fmaf(w0, bflo(u0.x), acc[0]); acc[1] = fmaf(w0, bfhi(u0.x), acc[1]);
        acc[2] = fmaf(w0, bflo(u0.y), acc[2]); acc[3] = fmaf(w0, bfhi(u0.y), acc[3]);
        acc[4] = fmaf(w0, bflo(u0.z), acc[4]); acc[5] = fmaf(w0, bfhi(u0.z), acc[5]);
        acc[6] = fmaf(w0, bflo(u0.w), acc[6]); acc[7] = fmaf(w0, bfhi(u0.w), acc[7]);
    }

    float inv = 1.f / (s + SM_EPS);
    unsigned int ov[4];
    #pragma unroll
    for (int j = 0; j < 4; ++j) {
        float v0 = acc[2 * j] * inv     + bias[cbase + 2 * j];
        float v1 = acc[2 * j + 1] * inv + bias[cbase + 2 * j + 1];
        v0 = v0 > 0.f ? v0 : __expf(v0) - 1.f;
        v1 = v1 > 0.f ? v1 : __expf(v1) - 1.f;
        ov[j] = (unsigned int)f2bf(v0) | ((unsigned int)f2bf(v1) << 16);
    }
    *(uint4*)(hout + (size_t)n * 512 + cbase) = make_uint4(ov[0], ov[1], ov[2], ov[3]);
}

// ---------------- GEMM2 (bf16 MFMA) + fused attn2; hw2 stored bf16 ----------------

__global__ __launch_bounds__(256) void k_gemm2_mfma(const unsigned short* __restrict__ A,
                                                    const unsigned short* __restrict__ Bt,
                                                    const float* __restrict__ att_s,
                                                    const float* __restrict__ att_d,
                                                    unsigned short* __restrict__ O,
                                                    float* __restrict__ a_s, float* __restrict__ a_d,
                                                    int M) {
    const int K = 512;
    __shared__ unsigned short As[64 * 40];
    __shared__ unsigned short Bs[32 * 40];
    int t = threadIdx.x;
    int lane = t & 63;
    int w = t >> 6;
    int row0 = blockIdx.x * 64;
    int l15 = lane & 15, q = lane >> 4;

    floatx4 acc[2] = {};

    for (int k0 = 0; k0 < K; k0 += 32) {
        {
            int flat = t * 8;
            int m = flat >> 5, kk = flat & 31;
            uint4 va = make_uint4(0u, 0u, 0u, 0u);
            int gr = row0 + m;
            if (gr < M) va = *(const uint4*)(A + (size_t)gr * K + k0 + kk);
            *(uint4*)(&As[m * 40 + kk]) = va;
            if (t < 128) {
                int nn = t >> 2, kb = (t & 3) * 8;
                *(uint4*)(&Bs[nn * 40 + kb]) = *(const uint4*)(Bt + (size_t)nn * K + k0 + kb);
            }
        }
        __syncthreads();
        short8 af = *(const short8*)(&As[(w * 16 + l15) * 40 + q * 8]);
        short8 b0 = *(const short8*)(&Bs[(l15) * 40 + q * 8]);
        short8 b1 = *(const short8*)(&Bs[(16 + l15) * 40 + q * 8]);
        acc[0] = __builtin_amdgcn_mfma_f32_16x16x32_bf16(af, b0, acc[0], 0, 0, 0);
        acc[1] = __builtin_amdgcn_mfma_f32_16x16x32_bf16(af, b1, acc[1], 0, 0, 0);
        __syncthreads();
    }

    float as_lo = att_s[l15], as_hi = att_s[16 + l15];
    float ad_lo = att_d[l15], ad_hi = att_d[16 + l15];
    #pragma unroll
    for (int p = 0; p < 4; ++p) {
        int r = row0 + w * 16 + q * 4 + p;
        bool ok = r < M;
        float v0 = acc[0][p], v1 = acc[1][p];
        if (ok) {
            O[(size_t)r * 32 + l15]      = f2bf(v0);
            O[(size_t)r * 32 + 16 + l15] = f2bf(v1);
        }
        float ds = v0 * as_lo + v1 * as_hi;
        float dd = v0 * ad_lo + v1 * ad_hi;
        #pragma unroll
        for (int mk = 1; mk <= 8; mk <<= 1) {
            ds += __shfl_xor(ds, mk);
            dd += __shfl_xor(dd, mk);
        }
        if (ok && l15 == 0) { a_s[r] = ds; a_d[r] = dd; }
    }
}

// ---------------- layer-2: single-pass softmax + aggregation + log-softmax ----------------

__global__ __launch_bounds__(256) void k_l2(const unsigned short* __restrict__ hw2,
                                            const float* __restrict__ a_s,
                                            const float* __restrict__ a_d,
                                            const int* __restrict__ off,
                                            const int* __restrict__ src_s,
                                            const float* __restrict__ bias,
                                            float* __restrict__ outp, int N) {
    int wid = threadIdx.x >> 6, lane = threadIdx.x & 63;
    int n = blockIdx.x * 4 + wid;
    if (n >= N) return;
    int p0 = off[n], p1 = off[n + 1];
    float adv = a_d[n];
    int c = lane & 31, ep = lane >> 5;

    float acc = 0.f, s = 0.f;
    int p = p0;
    for (; p + 64 <= p1; p += 64) {
        int bsrc = src_s[p + lane];
        float e = a_s[bsrc] + adv;
        e = e > 0.f ? e : NEG_SLOPE * e;
        float w64 = __expf(e);
        #pragma unroll
        for (int j = 0; j < 64; j += 2) {
            int sj = __shfl(bsrc, j + ep);
            float wj = __shfl(w64, j + ep);
            s += wj;
            acc = fmaf(wj, bf2f(hw2[(size_t)sj * 32 + c]), acc);
        }
    }
    if (p < p1) {
        int nb = p1 - p;
        int bsrc = src_s[p + (lane < nb ? lane : 0)];
        float e = a_s[bsrc] + adv;
        e = e > 0.f ? e : NEG_SLOPE * e;
        float w64 = __expf(e);
        for (int j = 0; j < nb; j += 2) {
            int idx = j + ep;
            bool valid = idx < nb;
            int idc = valid ? idx : 0;
            int sj = __shfl(bsrc, idc);
            float wj = __shfl(w64, idc);
            if (valid) {
                s += wj;
                acc = fmaf(wj, bf2f(hw2[(size_t)sj * 32 + c]), acc);
            }
        }
    }
    acc += __shfl_xor(acc, 32);
    s   += __shfl_xor(s, 32);
    float v = acc / (s + SM_EPS) + bias[c];
    float mx = v;
    #pragma unroll
    for (int mk = 16; mk >= 1; mk >>= 1) mx = fmaxf(mx, __shfl_xor(mx, mk, 32));
    float ex = __expf(v - mx);
    float sum = ex;
    #pragma unroll
    for (int mk = 16; mk >= 1; mk >>= 1) sum += __shfl_xor(sum, mk, 32);
    if (lane < 32) outp[(size_t)n * 32 + c] = (v - mx) - __logf(sum);
}

// ---------------- launch ----------------

extern "C" void kernel_launch(void* const* d_in, const int* in_sizes, int n_in,
                              void* d_out, int out_size, void* d_ws, size_t ws_size,
                              hipStream_t stream) {
    const float* x   = (const float*)d_in[0];
    const int*   ei  = (const int*)d_in[1];
    const float* W1  = (const float*)d_in[2];
    const float* as1 = (const float*)d_in[3];
    const float* ad1 = (const float*)d_in[4];
    const float* b1  = (const float*)d_in[5];
    const float* W2  = (const float*)d_in[6];
    const float* as2 = (const float*)d_in[7];
    const float* ad2 = (const float*)d_in[8];
    const float* b2  = (const float*)d_in[9];
    float* out = (float*)d_out;

    const int F = 512;
    const int N = in_sizes[0] / F;     // 20000
    const int E = in_sizes[1] / 2;     // 320000
    const int Ep = E + N;              // with self-loops
    const int* srcA = ei;
    const int* dstA = ei + E;

    char* w = (char*)d_ws;
    auto alloc = [&](size_t b) -> void* {
        void* p = (void*)w;
        w += (b + 255) & ~(size_t)255;
        return p;
    };
    unsigned short* xbf  = (unsigned short*)alloc((size_t)N * 512 * 2);
    unsigned short* w1t  = (unsigned short*)alloc((size_t)512 * 512 * 2);
    unsigned short* w2bt = (unsigned short*)alloc((size_t)32 * 512 * 2);
    unsigned short* xw1  = (unsigned short*)alloc((size_t)N * 512 * 2);
    unsigned short* hbuf = (unsigned short*)alloc((size_t)N * 512 * 2);   // bf16 h
    float* a_s1 = (float*)alloc((size_t)N * 8 * 4);   // head-major [8][N]
    float* a_d1 = (float*)alloc((size_t)N * 8 * 4);   // head-major [8][N]
    unsigned short* hw2 = (unsigned short*)alloc((size_t)N * 32 * 2);    // bf16 hw2
    float* a_s2 = (float*)alloc((size_t)N * 4);
    float* a_d2 = (float*)alloc((size_t)N * 4);
    int* deg    = (int*)alloc((size_t)N * 4);
    int* incl   = (int*)alloc((size_t)N * 4);
    int* part   = (int*)alloc(256 * 4);
    int* off    = (int*)alloc((size_t)(N + 1) * 4);
    int* cursor = (int*)alloc((size_t)N * 4);
    int* src_s  = (int*)alloc((size_t)Ep * 4);

    int egrid = (Ep + 255) / 256;
    int sgrid = (N + 255) / 256;
    int ngrid4 = (N + 3) / 4;
    int nblk_x = (N * 512 / 4) / 256;           // 10000
    int nblk_w2 = (32 * 512 + 255) / 256;       // 64

    hipMemsetAsync(deg, 0, (size_t)N * 4, stream);

    // fused prep: deg | x cast | W1t | W2t
    k_prep<<<egrid + nblk_x + 256 + nblk_w2, 256, 0, stream>>>(
        x, xbf, W1, w1t, W2, w2bt, dstA, E, Ep, deg, egrid, nblk_x);

    // CSR (shared by both layers)
    k_scan1<<<sgrid, 256, 0, stream>>>(deg, incl, part, N);
    k_scan3<<<sgrid, 256, 0, stream>>>(incl, part, deg, off, cursor, N);
    k_scatter<<<egrid, 256, 0, stream>>>(srcA, dstA, E, Ep, cursor, src_s);

    // layer 1
    {
        dim3 g1((N + 127) / 128, 512 / 128);
        k_gemm1_mfma<<<g1, 256, 0, stream>>>(xbf, w1t, as1, ad1, xw1, a_s1, a_d1, N);
    }
    {
        int ngrid32 = (N + 31) / 32;           // node groups of 32
        k_l1<<<ngrid32 * 8, 256, 0, stream>>>(xw1, a_s1, a_d1, off, src_s, b1, hbuf, N);
    }

    // layer 2
    k_gemm2_mfma<<<(N + 63) / 64, 256, 0, stream>>>(hbuf, w2bt, as2, ad2, hw2, a_s2, a_d2, N);
    k_l2<<<ngrid4, 256, 0, stream>>>(hw2, a_s2, a_d2, off, src_s, b2, out, N);
}